// Round 1
// baseline (34.834 us; speedup 1.0000x reference)
//
#include <hip/hip_runtime.h>
#include <math.h>

// Problem constants (fixed by the reference)
constexpr int NQ   = 33;        // N+1
constexpr int NSQ  = NQ * NQ;   // 1089
constexpr int NL   = 8;         // node labels
constexpr int NEL  = 4;         // edge labels
constexpr int NN   = 32;        // N
constexpr int ITERS = 10;       // sinkhorn iterations
constexpr int BLK  = 256;

// One block per pair. Computes ged[p] into ged_out.
__global__ __launch_bounds__(BLK) void ged_kernel(
    const float* __restrict__ nw, const float* __restrict__ ew,
    const int* __restrict__ A, const int* __restrict__ labels,
    const int* __restrict__ pairs, float* __restrict__ ged_out)
{
    __shared__ float S[NQ][NQ];            // sinkhorn matrix V
    __shared__ float Dm[NQ][NQ];           // node-cost matrix (c_diag)
    __shared__ float H[5][NQ][NQ];         // H[x][k][i] = sum_l f(x,A2[k,l]) V[i,l]
    __shared__ unsigned char A1s[NQ][NQ];
    __shared__ unsigned char A2s[NQ][NQ];
    __shared__ float ncost[NL][NL];
    __shared__ float ec[NEL][NEL];
    __shared__ float rfac[NQ];
    __shared__ float sNID, sEID;
    __shared__ int l1s[NN], l2s[NN];
    __shared__ float wredq[BLK/64], wredl[BLK/64];

    const int t = threadIdx.x;
    const int p = blockIdx.x;
    const int g1 = pairs[2*p+0];
    const int g2 = pairs[2*p+1];

    // --- tiny cost tables (thread 0) ---
    if (t == 0) {
        int idx = 0;
        for (int i = 0; i < NL; ++i) ncost[i][i] = 0.f;
        for (int i = 0; i < NL; ++i)
            for (int j = i+1; j < NL; ++j) {
                float v = fmaxf(nw[idx], 0.f); ++idx;
                ncost[i][j] = v; ncost[j][i] = v;
            }
        sNID = fmaxf(nw[idx], 0.f);   // nw[28]
        idx = 0;
        for (int i = 0; i < NEL; ++i) ec[i][i] = 0.f;
        for (int i = 0; i < NEL; ++i)
            for (int j = i+1; j < NEL; ++j) {
                float v = fmaxf(ew[idx], 0.f); ++idx;
                ec[i][j] = v; ec[j][i] = v;
            }
        sEID = fmaxf(ew[idx], 0.f);   // ew[6]
    }
    if (t < NN) {
        l1s[t] = labels[g1*NN + t];
        l2s[t] = labels[g2*NN + t];
    }
    // padded adjacency (labels 0..4), u8 in LDS
    for (int idx = t; idx < NSQ; idx += BLK) {
        int i = idx / NQ, j = idx - i*NQ;
        int a1 = (i < NN && j < NN) ? A[g1*NN*NN + i*NN + j] : 0;
        int a2 = (i < NN && j < NN) ? A[g2*NN*NN + i*NN + j] : 0;
        A1s[i][j] = (unsigned char)a1;
        A2s[i][j] = (unsigned char)a2;
    }
    __syncthreads();

    const float NID = sNID, EID = sEID;

    // --- Dmat and S0 = exp(-0.5*Dmat) ---
    for (int idx = t; idx < NSQ; idx += BLK) {
        int i = idx / NQ, j = idx - i*NQ;
        float d;
        if (i < NN && j < NN)              d = ncost[l1s[i]][l2s[j]];
        else if (i == NQ-1 && j == NQ-1)   d = 0.f;
        else                               d = NID;
        Dm[i][j] = d;
        S[i][j]  = expf(-0.5f * d);
    }
    __syncthreads();

    // --- sinkhorn: 10 iterations of row-normalize then col-normalize ---
    for (int it = 0; it < ITERS; ++it) {
        if (t < NQ) {
            float s = 0.f;
            #pragma unroll
            for (int j = 0; j < NQ; ++j) s += S[t][j];
            rfac[t] = (t == NQ-1) ? 1.f : 1.f / s;
        }
        __syncthreads();
        for (int idx = t; idx < NSQ; idx += BLK) {
            int i = idx / NQ;
            S[i][idx - i*NQ] *= rfac[i];
        }
        __syncthreads();
        if (t < NQ) {
            float s = 0.f;
            #pragma unroll
            for (int i = 0; i < NQ; ++i) s += S[i][t];
            rfac[t] = (t == NQ-1) ? 1.f : 1.f / s;
        }
        __syncthreads();
        for (int idx = t; idx < NSQ; idx += BLK) {
            int i = idx / NQ, j = idx - i*NQ;
            S[i][j] *= rfac[j];
        }
        __syncthreads();
    }

    // --- stage 1: H[x][k][i] via label-partial sums over l ---
    for (int idx = t; idx < NSQ; idx += BLK) {
        int k = idx / NQ, i = idx - k*NQ;
        float p0=0.f, p1=0.f, p2=0.f, p3=0.f, p4=0.f;
        #pragma unroll
        for (int l = 0; l < NQ; ++l) {
            float v = S[i][l];
            int a2 = A2s[k][l];
            p0 += (a2 == 0) ? v : 0.f;
            p1 += (a2 == 1) ? v : 0.f;
            p2 += (a2 == 2) ? v : 0.f;
            p3 += (a2 == 3) ? v : 0.f;
            p4 += (a2 == 4) ? v : 0.f;
        }
        H[0][k][i] = EID * (p1 + p2 + p3 + p4);
        #pragma unroll
        for (int x = 1; x <= 4; ++x) {
            H[x][k][i] = EID * p0
                       + ec[x-1][0]*p1 + ec[x-1][1]*p2
                       + ec[x-1][2]*p3 + ec[x-1][3]*p4;
        }
    }
    __syncthreads();

    // --- stage 2: quad = sum_{i,j} sum_k V[j,k] * H[A1[i,j]][k][i];  linear = <Dm, V> ---
    float qpart = 0.f, lpart = 0.f;
    for (int idx = t; idx < NSQ; idx += BLK) {
        int i = idx / NQ, j = idx - i*NQ;
        int x = A1s[i][j];
        const float* Hx = &H[x][0][i];
        float dot = 0.f;
        #pragma unroll
        for (int k = 0; k < NQ; ++k) dot += S[j][k] * Hx[k*NQ];
        qpart += dot;
        lpart += Dm[i][j] * S[i][j];
    }

    // block reduce (4 waves of 64)
    #pragma unroll
    for (int off = 32; off > 0; off >>= 1) {
        qpart += __shfl_down(qpart, off);
        lpart += __shfl_down(lpart, off);
    }
    const int wid = t >> 6, lane = t & 63;
    if (lane == 0) { wredq[wid] = qpart; wredl[wid] = lpart; }
    __syncthreads();
    if (t == 0) {
        float q = 0.f, l = 0.f;
        for (int w = 0; w < BLK/64; ++w) { q += wredq[w]; l += wredl[w]; }
        ged_out[p] = 0.5f * q + l;
    }
}

// Normalize: out = (ged - min)/(max - min)
__global__ __launch_bounds__(256) void norm_kernel(
    const float* __restrict__ ged, float* __restrict__ out, int P)
{
    __shared__ float smn[4], smx[4];
    int t = threadIdx.x;
    float mn = 1e30f, mx = -1e30f;
    for (int i = t; i < P; i += 256) {
        float g = ged[i];
        mn = fminf(mn, g); mx = fmaxf(mx, g);
    }
    #pragma unroll
    for (int off = 32; off > 0; off >>= 1) {
        mn = fminf(mn, __shfl_xor(mn, off));
        mx = fmaxf(mx, __shfl_xor(mx, off));
    }
    if ((t & 63) == 0) { smn[t>>6] = mn; smx[t>>6] = mx; }
    __syncthreads();
    mn = fminf(fminf(smn[0], smn[1]), fminf(smn[2], smn[3]));
    mx = fmaxf(fmaxf(smx[0], smx[1]), fmaxf(smx[2], smx[3]));
    float inv = 1.f / (mx - mn);
    for (int i = t; i < P; i += 256) out[i] = (ged[i] - mn) * inv;
}

extern "C" void kernel_launch(void* const* d_in, const int* in_sizes, int n_in,
                              void* d_out, int out_size, void* d_ws, size_t ws_size,
                              hipStream_t stream) {
    const float* nw     = (const float*)d_in[0];
    const float* ew     = (const float*)d_in[1];
    const int*   A      = (const int*)d_in[2];
    const int*   labels = (const int*)d_in[3];
    const int*   pairs  = (const int*)d_in[4];
    const int P = in_sizes[4] / 2;

    float* ged_ws = (float*)d_ws;

    ged_kernel<<<P, BLK, 0, stream>>>(nw, ew, A, labels, pairs, ged_ws);
    norm_kernel<<<1, 256, 0, stream>>>(ged_ws, (float*)d_out, P);
}

// Round 2
// 31.300 us; speedup vs baseline: 1.1129x; 1.1129x over previous
//
#include <hip/hip_runtime.h>
#include <math.h>

// Problem constants (fixed by the reference)
constexpr int NQ    = 33;        // N+1
constexpr int NQP   = 34;        // padded leading dim (bank-conflict-free strides)
constexpr int NSQ   = NQ * NQ;   // 1089
constexpr int NL    = 8;         // node labels
constexpr int NEL   = 4;         // edge labels
constexpr int NN    = 32;        // N
constexpr int ITERS = 10;        // sinkhorn iterations
constexpr int BLK   = 1024;
constexpr int RT    = 16;        // threads per row/col in sinkhorn sums
constexpr int SUMT  = NQ * RT;   // 528

// One block per pair; last finishing block also does the min/max normalization.
__global__ __launch_bounds__(BLK) void ged_fused(
    const float* __restrict__ nw, const float* __restrict__ ew,
    const int* __restrict__ A, const int* __restrict__ labels,
    const int* __restrict__ pairs, float* __restrict__ ged_ws,
    unsigned int* __restrict__ counter, float* __restrict__ out, int P)
{
    __shared__ float S[NQ][NQP];             // sinkhorn matrix V
    __shared__ float H[5][NQ][NQP];          // H[x][k][i] = sum_l f(x,A2[k,l]) V[i,l]
    __shared__ unsigned char A1s[NQ][NQ];
    __shared__ unsigned char A2s[NQ][NQ];
    __shared__ float ncost[NL][NL];
    __shared__ float ec[NEL][NEL];
    __shared__ float rfac[NQ], cfac[NQ];
    __shared__ float sNID, sEID;
    __shared__ int l1s[NN], l2s[NN];
    __shared__ float wredq[BLK/64], wredl[BLK/64];
    __shared__ int sdone;

    const int t  = threadIdx.x;
    const int p  = blockIdx.x;
    const int g1 = pairs[2*p+0], g2 = pairs[2*p+1];

    // --- tiny cost tables (thread 0) ---
    if (t == 0) {
        int idx = 0;
        for (int i = 0; i < NL; ++i) ncost[i][i] = 0.f;
        for (int i = 0; i < NL; ++i)
            for (int j = i+1; j < NL; ++j) {
                float v = fmaxf(nw[idx++], 0.f);
                ncost[i][j] = v; ncost[j][i] = v;
            }
        sNID = fmaxf(nw[idx], 0.f);          // nw[28]
        idx = 0;
        for (int i = 0; i < NEL; ++i) ec[i][i] = 0.f;
        for (int i = 0; i < NEL; ++i)
            for (int j = i+1; j < NEL; ++j) {
                float v = fmaxf(ew[idx++], 0.f);
                ec[i][j] = v; ec[j][i] = v;
            }
        sEID = fmaxf(ew[idx], 0.f);          // ew[6]
    }
    if (t >= 64  && t < 64 + NN)  l1s[t - 64]  = labels[g1*NN + (t - 64)];
    if (t >= 128 && t < 128 + NN) l2s[t - 128] = labels[g2*NN + (t - 128)];
    // padded adjacency (labels 0..4) as u8 in LDS
    for (int c = t; c < NSQ; c += BLK) {
        int i = c / NQ, j = c - i*NQ;
        int a1 = (i < NN && j < NN) ? A[g1*NN*NN + i*NN + j] : 0;
        int a2 = (i < NN && j < NN) ? A[g2*NN*NN + i*NN + j] : 0;
        A1s[i][j] = (unsigned char)a1;
        A2s[i][j] = (unsigned char)a2;
    }
    __syncthreads();

    const float NID = sNID, EID = sEID;

    // --- S0 = exp(-0.5*Dmat) (Dmat recomputed later, not stored) ---
    for (int c = t; c < NSQ; c += BLK) {
        int i = c / NQ, j = c - i*NQ;
        float d = (i < NN && j < NN) ? ncost[l1s[i]][l2s[j]]
                                     : ((i == NN && j == NN) ? 0.f : NID);
        S[i][j] = __expf(-0.5f * d);
    }
    __syncthreads();

    // --- sinkhorn: 3 passes / 3 barriers per iteration ---
    // row sums -> r;  col sums of r-scaled S -> c;  S *= r[i]*c[j]
    const int rr = t >> 4, sub = t & 15;   // valid for t < SUMT (16-aligned lane groups)
    for (int it = 0; it < ITERS; ++it) {
        if (t < SUMT) {
            float s = S[rr][sub] + S[rr][sub+16] + ((sub == 0) ? S[rr][32] : 0.f);
            s += __shfl_down(s, 8); s += __shfl_down(s, 4);
            s += __shfl_down(s, 2); s += __shfl_down(s, 1);
            if (sub == 0) rfac[rr] = (rr == NQ-1) ? 1.f : 1.f / s;
        }
        __syncthreads();
        if (t < SUMT) {
            float s = S[sub][rr]*rfac[sub] + S[sub+16][rr]*rfac[sub+16]
                    + ((sub == 0) ? S[32][rr]*rfac[32] : 0.f);
            s += __shfl_down(s, 8); s += __shfl_down(s, 4);
            s += __shfl_down(s, 2); s += __shfl_down(s, 1);
            if (sub == 0) cfac[rr] = (rr == NQ-1) ? 1.f : 1.f / s;
        }
        __syncthreads();
        for (int c = t; c < NSQ; c += BLK) {
            int i = c / NQ, j = c - i*NQ;
            S[i][j] *= rfac[i] * cfac[j];
        }
        __syncthreads();
    }

    // --- stage 1: H[x][k][i] via label-partial sums over l ---
    // c -> (i, k): consecutive lanes share i (S row broadcast), consecutive k
    for (int c = t; c < NSQ; c += BLK) {
        int i = c / NQ, k = c - i*NQ;
        float p0=0.f, p1=0.f, p2=0.f, p3=0.f, p4=0.f;
        #pragma unroll
        for (int l = 0; l < NQ; ++l) {
            float v = S[i][l];
            int a2 = A2s[k][l];
            p0 += (a2 == 0) ? v : 0.f;
            p1 += (a2 == 1) ? v : 0.f;
            p2 += (a2 == 2) ? v : 0.f;
            p3 += (a2 == 3) ? v : 0.f;
            p4 += (a2 == 4) ? v : 0.f;
        }
        H[0][k][i] = EID * (p1 + p2 + p3 + p4);
        #pragma unroll
        for (int x = 1; x <= 4; ++x) {
            H[x][k][i] = EID * p0
                       + ec[x-1][0]*p1 + ec[x-1][1]*p2
                       + ec[x-1][2]*p3 + ec[x-1][3]*p4;
        }
    }
    __syncthreads();

    // --- stage 2: quad = sum_{i,j} sum_k V[j,k] * H[A1[i,j]][k][i];  linear = <D, V> ---
    float qpart = 0.f, lpart = 0.f;
    for (int c = t; c < NSQ; c += BLK) {
        int i = c / NQ, j = c - i*NQ;
        int x = A1s[i][j];
        const float* Hx = &H[x][0][i];
        const float* Sj = &S[j][0];
        float dot = 0.f;
        #pragma unroll
        for (int k = 0; k < NQ; ++k) dot += Sj[k] * Hx[k*NQP];
        qpart += dot;
        float d = (i < NN && j < NN) ? ncost[l1s[i]][l2s[j]]
                                     : ((i == NN && j == NN) ? 0.f : NID);
        lpart += d * S[i][j];
    }

    // block reduce (16 waves)
    #pragma unroll
    for (int off = 32; off > 0; off >>= 1) {
        qpart += __shfl_down(qpart, off);
        lpart += __shfl_down(lpart, off);
    }
    if ((t & 63) == 0) { wredq[t>>6] = qpart; wredl[t>>6] = lpart; }
    __syncthreads();
    if (t == 0) {
        float q = 0.f, l = 0.f;
        for (int w = 0; w < BLK/64; ++w) { q += wredq[w]; l += wredl[w]; }
        ged_ws[p] = 0.5f * q + l;
        __threadfence();                       // release: ged visible device-wide
        unsigned int prev = atomicAdd(counter, 1u);
        sdone = (prev == (unsigned int)(gridDim.x - 1)) ? 1 : 0;
    }
    __syncthreads();

    // --- last block normalizes: out = (ged - min)/(max - min) ---
    if (sdone && t < 64) {
        __threadfence();                       // acquire: see other blocks' ged
        float mn = 1e30f, mx = -1e30f;
        for (int q0 = t; q0 < P; q0 += 64) {
            float g = ged_ws[q0];
            mn = fminf(mn, g); mx = fmaxf(mx, g);
        }
        #pragma unroll
        for (int off = 32; off > 0; off >>= 1) {
            mn = fminf(mn, __shfl_xor(mn, off));
            mx = fmaxf(mx, __shfl_xor(mx, off));
        }
        float inv = 1.f / (mx - mn);
        for (int q0 = t; q0 < P; q0 += 64) out[q0] = (ged_ws[q0] - mn) * inv;
    }
}

extern "C" void kernel_launch(void* const* d_in, const int* in_sizes, int n_in,
                              void* d_out, int out_size, void* d_ws, size_t ws_size,
                              hipStream_t stream) {
    const float* nw     = (const float*)d_in[0];
    const float* ew     = (const float*)d_in[1];
    const int*   A      = (const int*)d_in[2];
    const int*   labels = (const int*)d_in[3];
    const int*   pairs  = (const int*)d_in[4];
    const int P = in_sizes[4] / 2;

    float* ged_ws = (float*)d_ws;
    unsigned int* counter = (unsigned int*)((char*)d_ws + 256);

    hipMemsetAsync(counter, 0, sizeof(unsigned int), stream);
    ged_fused<<<P, BLK, 0, stream>>>(nw, ew, A, labels, pairs, ged_ws, counter,
                                     (float*)d_out, P);
}

// Round 4
// 20.966 us; speedup vs baseline: 1.6614x; 1.4928x over previous
//
#include <hip/hip_runtime.h>
#include <math.h>
#include <stdint.h>

// Problem constants (fixed by the reference)
constexpr int NQ    = 33;        // N+1
constexpr int NQP   = 34;        // padded leading dim (2-bank stride, conflict-free)
constexpr int NSQ   = NQ * NQ;   // 1089
constexpr int NL    = 8;         // node labels
constexpr int NEL   = 4;         // edge labels
constexpr int NN    = 32;        // N
constexpr int ITERS = 10;        // sinkhorn iterations
constexpr int BLK   = 1024;

// One block per pair. ged[p] -> ged_ws.
__global__ __launch_bounds__(BLK, 1) void ged_kernel(
    const float* __restrict__ nw, const float* __restrict__ ew,
    const int* __restrict__ A, const int* __restrict__ labels,
    const int* __restrict__ pairs, float* __restrict__ ged_ws)
{
    __shared__ float S[NQ][NQP];             // S0, scaled in place to final V
    __shared__ float S0T[NQ][NQP];           // S0 transposed (for col matvec)
    __shared__ float H[5][NQ][NQP];          // H[x][i][k] = sum_l f(x,A2[k,l]) V[i,l]
    __shared__ unsigned char A1s[NQ][36];    // padded rows, word-readable
    __shared__ unsigned char A2s[NQ][36];
    __shared__ float ncost[NL][NL];
    __shared__ float encost[NL][NL];         // exp(-0.5*ncost)
    __shared__ float ec[NEL][NEL];
    __shared__ float rr[NQ], cc[NQ];
    __shared__ float sNID, sEID, sENID;
    __shared__ int l1s[NN], l2s[NN];
    __shared__ float wredq[BLK/64], wredl[BLK/64];

    const int t  = threadIdx.x;
    const int p  = blockIdx.x;
    const int g1 = pairs[2*p+0], g2 = pairs[2*p+1];

    // ---- phase A: tables (wave 0 lanes), labels, adjacency ----
    if (t < 28) {                            // node substitution costs
        int i = (t>=27)?6 : (t>=25)?5 : (t>=22)?4 : (t>=18)?3 : (t>=13)?2 : (t>=7)?1 : 0;
        int off = (i==0)?0 : (i==1)?7 : (i==2)?13 : (i==3)?18 : (i==4)?22 : (i==5)?25 : 27;
        int j = t - off + i + 1;
        float v = fmaxf(nw[t], 0.f);
        ncost[i][j] = v; ncost[j][i] = v;
        float e = __expf(-0.5f * v);
        encost[i][j] = e; encost[j][i] = e;
    } else if (t == 28) {
        float v = fmaxf(nw[28], 0.f);
        sNID = v; sENID = __expf(-0.5f * v);
    } else if (t >= 32 && t < 38) {          // edge substitution costs
        int q = t - 32;
        // triu_indices(4,k=1): (0,1)(0,2)(0,3)(1,2)(1,3)(2,3)
        int ei = (q<3)?0 : (q<5)?1 : 2;
        int ej = (q<3)?q+1 : (q<5)?q-1 : 3;
        float v = fmaxf(ew[q], 0.f);
        ec[ei][ej] = v; ec[ej][ei] = v;
    } else if (t == 38) {
        sEID = fmaxf(ew[6], 0.f);
    } else if (t >= 40 && t < 48) {          // diagonals
        int q = t - 40;
        ncost[q][q] = 0.f; encost[q][q] = 1.f;
    } else if (t >= 48 && t < 52) {
        int q = t - 48;
        ec[q][q] = 0.f;
    } else if (t >= 56 && t < 56 + NQ) {
        cc[t - 56] = 1.f;                    // sinkhorn col-scale init
    }
    if (t >= 64  && t < 64 + NN)  l1s[t - 64]  = labels[g1*NN + (t - 64)];
    if (t >= 96  && t < 96 + NN)  l2s[t - 96]  = labels[g2*NN + (t - 96)];
    for (int c0 = t; c0 < NSQ; c0 += BLK) {
        int i = c0 / NQ, j = c0 - i*NQ;
        int a1 = (i < NN && j < NN) ? A[g1*NN*NN + i*NN + j] : 0;
        int a2 = (i < NN && j < NN) ? A[g2*NN*NN + i*NN + j] : 0;
        A1s[i][j] = (unsigned char)a1;
        A2s[i][j] = (unsigned char)a2;
    }
    __syncthreads();

    const float NID = sNID, EID = sEID, ENID = sENID;

    // ---- phase B: S0 (and transpose) from encost table ----
    for (int c0 = t; c0 < NSQ; c0 += BLK) {
        int i = c0 / NQ, j = c0 - i*NQ;
        float e = (i < NN && j < NN) ? encost[l1s[i]][l2s[j]]
                                     : ((i == NN && j == NN) ? 1.f : ENID);
        S[i][j]   = e;
        S0T[j][i] = e;
    }
    __syncthreads();

    // ---- phase C: sinkhorn on wave 0, scaling form, zero barriers ----
    // r[i] = 1/sum_j S0[i][j]*c[j]  (i<32; r[32]=1)
    // c[j] = 1/sum_i S0[i][j]*r[i]  (j<32; c[32]=1)
    if (t < NQ) {
        for (int it = 0; it < ITERS; ++it) {
            float s = 0.f;
            #pragma unroll
            for (int j = 0; j < NQ; ++j) s += S[t][j] * cc[j];
            rr[t] = (t == NQ-1) ? 1.f : __builtin_amdgcn_rcpf(s);
            float s2 = 0.f;
            #pragma unroll
            for (int i2 = 0; i2 < NQ; ++i2) s2 += S0T[t][i2] * rr[i2];
            cc[t] = (t == NQ-1) ? 1.f : __builtin_amdgcn_rcpf(s2);
        }
    }
    __syncthreads();

    // ---- phase D: materialize V = diag(r) S0 diag(c) in place ----
    for (int c0 = t; c0 < NSQ; c0 += BLK) {
        int i = c0 / NQ, j = c0 - i*NQ;
        S[i][j] *= rr[i] * cc[j];
    }
    __syncthreads();

    // ---- phase E: H[x][i][k] = sum_l f(x, A2[k,l]) V[i,l] ----
    for (int c0 = t; c0 < NSQ; c0 += BLK) {
        int i = c0 / NQ, k = c0 - i*NQ;
        const float* Si = &S[i][0];
        const uint32_t* Aw = (const uint32_t*)&A2s[k][0];
        float p0=0.f, p1=0.f, p2=0.f, p3=0.f, p4=0.f;
        #pragma unroll
        for (int l = 0; l < NQ; ++l) {
            float v = Si[l];
            int a2 = (int)((Aw[l >> 2] >> ((l & 3) * 8)) & 255u);
            p0 += (a2 == 0) ? v : 0.f;
            p1 += (a2 == 1) ? v : 0.f;
            p2 += (a2 == 2) ? v : 0.f;
            p3 += (a2 == 3) ? v : 0.f;
            p4 += (a2 == 4) ? v : 0.f;
        }
        H[0][i][k] = EID * (p1 + p2 + p3 + p4);
        #pragma unroll
        for (int x = 1; x <= 4; ++x) {
            H[x][i][k] = EID * p0
                       + ec[x-1][0]*p1 + ec[x-1][1]*p2
                       + ec[x-1][2]*p3 + ec[x-1][3]*p4;
        }
    }
    __syncthreads();

    // ---- phase F: quad + linear ----
    float qpart = 0.f, lpart = 0.f;
    const float* Hb = &H[0][0][0];
    for (int c0 = t; c0 < NSQ; c0 += BLK) {
        int i = c0 / NQ, j = c0 - i*NQ;
        int x = A1s[i][j];
        const float* Hx = Hb + x*(NQ*NQP) + i*NQP;
        const float* Sj = &S[j][0];
        float dot = 0.f;
        #pragma unroll
        for (int k = 0; k < NQ; ++k) dot += Sj[k] * Hx[k];
        qpart += dot;
        float d = (i < NN && j < NN) ? ncost[l1s[i]][l2s[j]]
                                     : ((i == NN && j == NN) ? 0.f : NID);
        lpart += d * S[i][j];
    }

    #pragma unroll
    for (int off = 32; off > 0; off >>= 1) {
        qpart += __shfl_down(qpart, off);
        lpart += __shfl_down(lpart, off);
    }
    if ((t & 63) == 0) { wredq[t>>6] = qpart; wredl[t>>6] = lpart; }
    __syncthreads();
    if (t == 0) {
        float q = 0.f, l = 0.f;
        #pragma unroll
        for (int w = 0; w < BLK/64; ++w) { q += wredq[w]; l += wredl[w]; }
        ged_ws[p] = 0.5f * q + l;
    }
}

// out = (ged - min)/(max - min)
__global__ __launch_bounds__(64) void norm_kernel(
    const float* __restrict__ ged, float* __restrict__ out, int P)
{
    int t = threadIdx.x;
    float mn = 1e30f, mx = -1e30f;
    for (int i = t; i < P; i += 64) {
        float g = ged[i];
        mn = fminf(mn, g); mx = fmaxf(mx, g);
    }
    #pragma unroll
    for (int off = 32; off > 0; off >>= 1) {
        mn = fminf(mn, __shfl_xor(mn, off));
        mx = fmaxf(mx, __shfl_xor(mx, off));
    }
    float inv = 1.f / (mx - mn);
    for (int i = t; i < P; i += 64) out[i] = (ged[i] - mn) * inv;
}

extern "C" void kernel_launch(void* const* d_in, const int* in_sizes, int n_in,
                              void* d_out, int out_size, void* d_ws, size_t ws_size,
                              hipStream_t stream) {
    const float* nw     = (const float*)d_in[0];
    const float* ew     = (const float*)d_in[1];
    const int*   A      = (const int*)d_in[2];
    const int*   labels = (const int*)d_in[3];
    const int*   pairs  = (const int*)d_in[4];
    const int P = in_sizes[4] / 2;

    float* ged_ws = (float*)d_ws;

    ged_kernel<<<P, BLK, 0, stream>>>(nw, ew, A, labels, pairs, ged_ws);
    norm_kernel<<<1, 64, 0, stream>>>(ged_ws, (float*)d_out, P);
}